// Round 4
// baseline (863.275 us; speedup 1.0000x reference)
//
#include <hip/hip_runtime.h>
#include <math.h>

#define NROWS 8192
#define DIM   256
#define NCLS  64
#define KNN   5
#define NCAND 8      // per (row, j-split)
#define NSPLIT 4
#define MAXSTEPS 100
#define ITER_GRID 2048

struct IterState {
  double Eold;
  int flag;       // converged
  int final_buf;  // parity of last-written Y buffer (0 = Ya, 1 = Yb)
};

typedef __attribute__((ext_vector_type(8))) short bf16x8;
typedef __attribute__((ext_vector_type(4))) float f32x4;

// ---------------- wave (64-lane) reductions ----------------
__device__ __forceinline__ float wave_max64(float v) {
#pragma unroll
  for (int m = 32; m >= 1; m >>= 1) v = fmaxf(v, __shfl_xor(v, m, 64));
  return v;
}
__device__ __forceinline__ float wave_sum64(float v) {
#pragma unroll
  for (int m = 32; m >= 1; m >>= 1) v += __shfl_xor(v, m, 64);
  return v;
}
__device__ __forceinline__ double wave_sum64d(double v) {
#pragma unroll
  for (int m = 32; m >= 1; m >>= 1) v += __shfl_xor(v, m, 64);
  return v;
}

__device__ __forceinline__ unsigned short f2bf(float x) {  // RNE bf16
  unsigned u = __float_as_uint(x);
  u += 0x7FFFu + ((u >> 16) & 1u);
  return (unsigned short)(u >> 16);
}

// ---------------- 1. normalize: write pre-swizzled bf16 tiles + nrm + sqd ----------------
// fb layout (uint4 granules, 16B = 8 bf16 dims): for global row r, tile T=r>>6,
// local row rl=r&63, granule g (dims 8g..8g+7):
//   fb_uint4[ T*2048 + rl*32 + (g ^ (rl&31)) ]
// This bakes the k_gram LDS swizzle into global memory so staging is a pure
// linear 32 KB copy.
__global__ void k_normalize(const float* __restrict__ feats, uint2* __restrict__ fb2,
                            float* __restrict__ nrm, double* __restrict__ sqd) {
  int row  = blockIdx.x * 4 + (threadIdx.x >> 6);
  int lane = threadIdx.x & 63;
  float4 v = ((const float4*)(feats + (size_t)row * DIM))[lane];
  double ss = (double)v.x * v.x + (double)v.y * v.y + (double)v.z * v.z + (double)v.w * v.w;
  ss = wave_sum64d(ss);
  float nr = fmaxf((float)sqrt(ss), 1e-12f);
  if (lane == 0) nrm[row] = nr;
  float4 o;  // exact fp32 division (matches k_refine's recompute bit-for-bit)
  o.x = v.x / nr; o.y = v.y / nr; o.z = v.z / nr; o.w = v.w / nr;
  // exact fp64 squared norm of the rounded fp32 normalized row -> refine keys
  double s2 = (double)o.x * o.x + (double)o.y * o.y + (double)o.z * o.z + (double)o.w * o.w;
  s2 = wave_sum64d(s2);
  if (lane == 0) sqd[row] = s2;
  // pack 4 bf16 -> uint2, swizzled granule write
  uint2 w2;
  w2.x = (unsigned)f2bf(o.x) | ((unsigned)f2bf(o.y) << 16);
  w2.y = (unsigned)f2bf(o.z) | ((unsigned)f2bf(o.w) << 16);
  int T = row >> 6, rl = row & 63, g = lane >> 1, h = lane & 1;
  fb2[((size_t)T * 2048 + rl * 32 + (g ^ (rl & 31))) * 2 + h] = w2;
}

// ---------------- 2. MFMA bf16 candidate Gram + per-row top-8 ----------------
// grid = 512 blocks: (row-block ib 0..127) x (j-split js 0..3).
// A-tile staged once (linear 32 KB copy of pre-swizzled fb tile), B-tiles
// prefetched in regs during MFMA of the previous tile. 4 waves x (2x2 of
// 16x16x32 bf16 MFMA) -> 64x64 C -> swizzled LDS -> per-thread top-8 -> merge.
// All LDS patterns identical to R2 (measured 0 bank conflicts).
#define JSPAN (NROWS / NSPLIT)  // 2048

__launch_bounds__(256, 2)
__global__ void k_gram(const uint4* __restrict__ fb, int* __restrict__ candp) {
  __shared__ uint4 Ash4[2048];   // 32 KB bf16, swizzled granules
  __shared__ uint4 Bsh4[2048];   // 32 KB
  __shared__ float Csh[64 * 64]; // 16 KB (reused as merge area)

  const int t  = threadIdx.x;
  const int ib = blockIdx.x >> 2;
  const int js = blockIdx.x & 3;
  const int i0 = ib * 64;
  const int jbase = js * JSPAN;

  // ---- stage A: linear copy of pre-swizzled tile ib ----
  {
    const uint4* At = fb + (size_t)ib * 2048;
#pragma unroll
    for (int p = 0; p < 8; ++p) Ash4[p * 256 + t] = At[p * 256 + t];
  }

  const int w = t >> 6, lane = t & 63;
  const int ihalf = w >> 1, jhalf = w & 1;
  const int m15 = lane & 15, quad = lane >> 4;

  float mv[NCAND]; int mi[NCAND];
#pragma unroll
  for (int k = 0; k < NCAND; ++k) { mv[k] = -1e30f; mi[k] = -1; }

  // prefetch B tile 0 (tile index js*32)
  uint4 fr[8];
  {
    const uint4* Bt = fb + (size_t)(js * 32) * 2048;
#pragma unroll
    for (int p = 0; p < 8; ++p) fr[p] = Bt[p * 256 + t];
  }

  for (int jt = 0; jt < JSPAN / 64; ++jt) {
    const int j0 = jt * 64;
    __syncthreads();  // (a) prev C reads done; A staged (first iter)
#pragma unroll
    for (int p = 0; p < 8; ++p) Bsh4[p * 256 + t] = fr[p];
    __syncthreads();  // (b) B visible

    if (jt + 1 < JSPAN / 64) {
      const uint4* Bt = fb + (size_t)(js * 32 + jt + 1) * 2048;
#pragma unroll
      for (int p = 0; p < 8; ++p) fr[p] = Bt[p * 256 + t];
    }

    f32x4 acc[2][2];
#pragma unroll
    for (int si = 0; si < 2; ++si)
#pragma unroll
      for (int sj = 0; sj < 2; ++sj) acc[si][sj] = (f32x4)(0.f);

#pragma unroll
    for (int kc = 0; kc < 8; ++kc) {
      const int g = kc * 4 + quad;
      bf16x8 av[2], bv[2];
#pragma unroll
      for (int s = 0; s < 2; ++s) {
        int ra = ihalf * 32 + s * 16 + m15;
        av[s] = ((const bf16x8*)Ash4)[ra * 32 + (g ^ (ra & 31))];
        int rb = jhalf * 32 + s * 16 + m15;
        bv[s] = ((const bf16x8*)Bsh4)[rb * 32 + (g ^ (rb & 31))];
      }
      acc[0][0] = __builtin_amdgcn_mfma_f32_16x16x32_bf16(av[0], bv[0], acc[0][0], 0, 0, 0);
      acc[0][1] = __builtin_amdgcn_mfma_f32_16x16x32_bf16(av[0], bv[1], acc[0][1], 0, 0, 0);
      acc[1][0] = __builtin_amdgcn_mfma_f32_16x16x32_bf16(av[1], bv[0], acc[1][0], 0, 0, 0);
      acc[1][1] = __builtin_amdgcn_mfma_f32_16x16x32_bf16(av[1], bv[1], acc[1][1], 0, 0, 0);
    }

    // C -> swizzled LDS. C layout: col=lane&15, row=quad*4+reg.
#pragma unroll
    for (int si = 0; si < 2; ++si)
#pragma unroll
      for (int sj = 0; sj < 2; ++sj)
#pragma unroll
        for (int r = 0; r < 4; ++r) {
          int col = jhalf * 32 + sj * 16 + m15;
          int row = ihalf * 32 + si * 16 + quad * 4 + r;
          int gc = col >> 2, sg = gc ^ (row & 15);
          Csh[row * 64 + sg * 4 + (col & 3)] = acc[si][sj][r];
        }
    __syncthreads();  // (c) C visible

    // top-8 insert: thread -> (row t>>2, cols (t&3)*16 .. +15)
    {
      int row = t >> 2, q = t & 3;
#pragma unroll
      for (int p = 0; p < 4; ++p) {
        int gc = q * 4 + p, sg = gc ^ (row & 15);
        float4 v = *(const float4*)&Csh[row * 64 + sg * 4];
        int jg = jbase + j0 + gc * 4;
        float vv[4] = {v.x, v.y, v.z, v.w};
#pragma unroll
        for (int s = 0; s < 4; ++s) {
          float val = vv[s];
          if (val > mv[NCAND - 1]) {
            mv[NCAND - 1] = val; mi[NCAND - 1] = jg + s;
#pragma unroll
            for (int k = NCAND - 1; k >= 1; --k) {
              if (mv[k] > mv[k - 1]) {
                float tv = mv[k]; mv[k] = mv[k - 1]; mv[k - 1] = tv;
                int ti = mi[k]; mi[k] = mi[k - 1]; mi[k - 1] = ti;
              }
            }
          }
        }
      }
    }
  }

  // ---- merge 4 per-thread lists per row -> top-8 per (row, split) ----
  __syncthreads();
  float* mergeV = Csh;                 // [64][32] swizzled
  int*   mergeI = (int*)(Csh + 2048);  // [64][32] swizzled
  {
    int row = t >> 2, q = t & 3;
#pragma unroll
    for (int k = 0; k < NCAND; ++k) {
      int pos = q * NCAND + k;
      mergeV[row * 32 + (pos ^ (row & 31))] = mv[k];
      mergeI[row * 32 + (pos ^ (row & 31))] = mi[k];
    }
  }
  __syncthreads();
  if (t < 64) {
    float fv[NCAND]; int fi[NCAND];
#pragma unroll
    for (int k = 0; k < NCAND; ++k) { fv[k] = -1e30f; fi[k] = -1; }
    for (int s = 0; s < 32; ++s) {
      float v = mergeV[t * 32 + (s ^ (t & 31))];
      int j = mergeI[t * 32 + (s ^ (t & 31))];
      if (v > fv[NCAND - 1]) {
        fv[NCAND - 1] = v; fi[NCAND - 1] = j;
#pragma unroll
        for (int k = NCAND - 1; k >= 1; --k) {
          if (fv[k] > fv[k - 1]) {
            float tv = fv[k]; fv[k] = fv[k - 1]; fv[k - 1] = tv;
            int ti = fi[k]; fi[k] = fi[k - 1]; fi[k - 1] = ti;
          }
        }
      }
    }
#pragma unroll
    for (int k = 0; k < NCAND; ++k)
      candp[(size_t)js * (NROWS * NCAND) + (size_t)(i0 + t) * NCAND + k] = fi[k];
  }
}

// ---------------- 3. fp64 exact refine: 32 candidates -> exact top-5 ----------------
// 4 rows per block (one row per wave). Normalized values recomputed as
// fl(feats/nrm) -- bit-identical to k_normalize's fp32 division.
__global__ void k_refine(const float* __restrict__ feats, const float* __restrict__ nrm,
                         const double* __restrict__ sqd, const int* __restrict__ candp,
                         int* __restrict__ nbr) {
  const int row = blockIdx.x * 4 + (threadIdx.x >> 6);
  const int t = threadIdx.x & 63;
  const int c = t >> 1;        // candidate 0..31
  const int seg = t & 1;       // half of D
  const int split = c >> 3, slot = c & 7;
  int j = candp[(size_t)split * (NROWS * NCAND) + (size_t)row * NCAND + slot];
  const float* fi = feats + (size_t)row * DIM;
  const float* fj = feats + (size_t)j * DIM;
  const float ni = nrm[row], nj = nrm[j];
  double dot = 0.0;
  const int dbase = seg * 128;
#pragma unroll 4
  for (int d = 0; d < 128; ++d) {
    float a = fi[dbase + d] / ni;   // correctly-rounded fp32 div
    float b = fj[dbase + d] / nj;
    dot = fma((double)a, (double)b, dot);
  }
  dot += __shfl_xor(dot, 1, 64);
  double key = sqd[j] - 2.0 * dot;   // == dist2 - sq_i (monotone in dist)
  bool valid = (seg == 0) && (j != row);   // exclude self (== reference idx[:,1:])
  for (int s = 0; s < KNN; ++s) {
    double v = valid ? key : (double)INFINITY;
    int vj = valid ? j : 0x7fffffff;
#pragma unroll
    for (int m = 1; m < 64; m <<= 1) {
      double ov = __shfl_xor(v, m, 64);
      int oj = __shfl_xor(vj, m, 64);
      if (ov < v || (ov == v && oj < vj)) { v = ov; vj = oj; }
    }
    if (valid && vj == j) valid = false;
    if (t == 0) nbr[(size_t)row * 8 + s] = vj;
  }
}

// ---------------- 4. unary + Y0 ----------------
__global__ void k_inity(const float* __restrict__ scores, float* __restrict__ unary,
                        float* __restrict__ Y) {
  int row = blockIdx.x * 4 + (threadIdx.x >> 6);
  int c = threadIdx.x & 63;
  float s = scores[(size_t)row * NCLS + c];
  float u = -logf(s + 1e-10f);
  unary[(size_t)row * NCLS + c] = u;
  float logit = -u;
  float m = wave_max64(logit);
  float e = expf(logit - m);
  float sum = wave_sum64(e);
  Y[(size_t)row * NCLS + c] = e / sum;
}

// ---------------- 5. mean-field iteration + fused convergence check ----------------
// E = sum(u*Y - pw*Y + Y*logY) collapses to -sum_rows lse (LAM == 1).
// 1 row per wave, grid 2048 -> 8 blocks/CU (32 waves) to hide gather latency.
__launch_bounds__(256, 8)
__global__ void k_iter(const float* __restrict__ Yin, float* __restrict__ Yout,
                       const float* __restrict__ unary, const int* __restrict__ nbr,
                       IterState* st, double* __restrict__ Epart,
                       int* __restrict__ ctr, int iter) {
  if (st->flag) return;
  const int w = threadIdx.x >> 6;
  const int lane = threadIdx.x & 63;
  const int row = blockIdx.x * 4 + w;
  const int* nb = nbr + (size_t)row * 8;
  float pw = 0.f;
#pragma unroll
  for (int k = 0; k < KNN; ++k) pw += Yin[(size_t)nb[k] * NCLS + lane];
  float logit = pw - unary[(size_t)row * NCLS + lane];
  float m = wave_max64(logit);
  float e = expf(logit - m);
  float sum = wave_sum64(e);
  Yout[(size_t)row * NCLS + lane] = e / sum;
  __shared__ double sE[4];
  __shared__ int isLast;
  if (lane == 0) sE[w] = -(double)(m + logf(sum));
  __syncthreads();
  if (threadIdx.x == 0) {
    Epart[blockIdx.x] = (sE[0] + sE[1]) + (sE[2] + sE[3]);
    __threadfence();
    int old = atomicAdd(&ctr[iter], 1);
    isLast = (old == ITER_GRID - 1);
  }
  __syncthreads();
  if (isLast) {
    __threadfence();  // acquire all Epart writes
    __shared__ double sd[256];
    double s = 0.0;
#pragma unroll
    for (int i = 0; i < ITER_GRID / 256; ++i) s += Epart[i * 256 + threadIdx.x];
    sd[threadIdx.x] = s;
    __syncthreads();
    for (int off = 128; off >= 1; off >>= 1) {
      if (threadIdx.x < off) sd[threadIdx.x] += sd[threadIdx.x + off];
      __syncthreads();
    }
    if (threadIdx.x == 0) {
      double E = sd[0];
      bool conv = (iter > 1) && (fabs(E - st->Eold) <= 1e-8 * fabs(st->Eold));
      st->final_buf = (iter + 1) & 1;  // this iter wrote buf[(iter+1)&1]
      if (conv) st->flag = 1;
      else st->Eold = E;
    }
  }
}

// ---------------- 0/7. state init + final copy ----------------
__global__ void k_init(IterState* st, int* ctr) {
  int t = threadIdx.x;
  if (t < MAXSTEPS) ctr[t] = 0;
  if (t == 255) { st->Eold = (double)INFINITY; st->flag = 0; st->final_buf = 0; }
}
__global__ void k_copy(const float* __restrict__ Ya, const float* __restrict__ Yb,
                       const IterState* __restrict__ st, float* __restrict__ out) {
  const float* src = st->final_buf ? Yb : Ya;
  int i = blockIdx.x * blockDim.x + threadIdx.x;
  ((float4*)out)[i] = ((const float4*)src)[i];
}

extern "C" void kernel_launch(void* const* d_in, const int* in_sizes, int n_in,
                              void* d_out, int out_size, void* d_ws, size_t ws_size,
                              hipStream_t stream) {
  (void)in_sizes; (void)n_in; (void)out_size; (void)ws_size;
  const float* scores = (const float*)d_in[0];
  const float* feats  = (const float*)d_in[1];
  float* out = (float*)d_out;
  char* ws = (char*)d_ws;
  // workspace layout (all 256B-aligned); total ~11.4 MB
  uint4*  fb    = (uint4*)(ws + 0);          //  4 MB pre-swizzled bf16 tiles
  float*  Ya    = (float*)(ws + 4194304);    //  2 MB
  float*  Yb    = (float*)(ws + 6291456);    //  2 MB
  float*  unary = (float*)(ws + 8388608);    //  2 MB
  double* sqd   = (double*)(ws + 10485760);  // 64 KB
  float*  nrm   = (float*)(ws + 10551296);   // 32 KB
  int*    candp = (int*)(ws + 10584064);     //  1 MB (4 splits x 8192 x 8)
  int*    nbr   = (int*)(ws + 11632640);     // 256 KB
  double* Epart = (double*)(ws + 11894784);  // 16 KB
  int*    ctr   = (int*)(ws + 11911168);     // 512 B
  IterState* st = (IterState*)(ws + 11911680);

  k_init<<<1, 256, 0, stream>>>(st, ctr);
  k_normalize<<<NROWS / 4, 256, 0, stream>>>(feats, (uint2*)fb, nrm, sqd);
  k_gram<<<(NROWS / 64) * NSPLIT, 256, 0, stream>>>(fb, candp);
  k_refine<<<NROWS / 4, 256, 0, stream>>>(feats, nrm, sqd, candp, nbr);
  k_inity<<<NROWS / 4, 256, 0, stream>>>(scores, unary, Ya);
  for (int k = 0; k < MAXSTEPS; ++k) {
    const float* yin = (k & 1) ? Yb : Ya;
    float* yout = (k & 1) ? Ya : Yb;
    k_iter<<<ITER_GRID, 256, 0, stream>>>(yin, yout, unary, nbr, st, Epart, ctr, k);
  }
  k_copy<<<512, 256, 0, stream>>>(Ya, Yb, st, out);
}

// Round 5
// 588.974 us; speedup vs baseline: 1.4657x; 1.4657x over previous
//
#include <hip/hip_runtime.h>
#include <math.h>

#define NROWS 8192
#define DIM   256
#define NCLS  64
#define KNN   5
#define NCAND 8      // per (row, j-split)
#define NSPLIT 4
#define MAXSTEPS 100
#define ITER_GRID 512

struct IterState {
  double Eold;
  int flag;       // converged
  int final_buf;  // parity of last-written Y buffer (0 = Ya, 1 = Yb)
};

typedef __attribute__((ext_vector_type(8))) short bf16x8;
typedef __attribute__((ext_vector_type(4))) float f32x4;

typedef __attribute__((address_space(1))) unsigned int glb_u32_t;
typedef __attribute__((address_space(3))) unsigned int lds_u32_t;
// async global->LDS DMA, 16 B per lane; LDS dest = wave-uniform base + lane*16
__device__ __forceinline__ void async_cp16(const uint4* g, uint4* l) {
  __builtin_amdgcn_global_load_lds((const glb_u32_t*)(const unsigned int*)g,
                                   (lds_u32_t*)(unsigned int*)l, 16, 0, 0);
}

// ---------------- wave (64-lane) reductions ----------------
__device__ __forceinline__ float wave_max64(float v) {
#pragma unroll
  for (int m = 32; m >= 1; m >>= 1) v = fmaxf(v, __shfl_xor(v, m, 64));
  return v;
}
__device__ __forceinline__ float wave_sum64(float v) {
#pragma unroll
  for (int m = 32; m >= 1; m >>= 1) v += __shfl_xor(v, m, 64);
  return v;
}
__device__ __forceinline__ double wave_sum64d(double v) {
#pragma unroll
  for (int m = 32; m >= 1; m >>= 1) v += __shfl_xor(v, m, 64);
  return v;
}

__device__ __forceinline__ unsigned short f2bf(float x) {  // RNE bf16
  unsigned u = __float_as_uint(x);
  u += 0x7FFFu + ((u >> 16) & 1u);
  return (unsigned short)(u >> 16);
}

// ---------------- 1. normalize: write pre-swizzled bf16 tiles + nrm + sqd ----------------
// fb layout (uint4 granules, 16B = 8 bf16 dims): for global row r, tile T=r>>6,
// local row rl=r&63, granule g (dims 8g..8g+7):
//   fb_uint4[ T*2048 + rl*32 + (g ^ (rl&31)) ]
// Bakes the k_gram LDS swizzle into global memory so staging is a pure linear
// copy (DMA-compatible: LDS slot index == linear offset within the tile).
__global__ void k_normalize(const float* __restrict__ feats, uint2* __restrict__ fb2,
                            float* __restrict__ nrm, double* __restrict__ sqd) {
  int row  = blockIdx.x * 4 + (threadIdx.x >> 6);
  int lane = threadIdx.x & 63;
  float4 v = ((const float4*)(feats + (size_t)row * DIM))[lane];
  double ss = (double)v.x * v.x + (double)v.y * v.y + (double)v.z * v.z + (double)v.w * v.w;
  ss = wave_sum64d(ss);
  float nr = fmaxf((float)sqrt(ss), 1e-12f);
  if (lane == 0) nrm[row] = nr;
  float4 o;  // exact fp32 division (matches k_refine's recompute bit-for-bit)
  o.x = v.x / nr; o.y = v.y / nr; o.z = v.z / nr; o.w = v.w / nr;
  // exact fp64 squared norm of the rounded fp32 normalized row -> refine keys
  double s2 = (double)o.x * o.x + (double)o.y * o.y + (double)o.z * o.z + (double)o.w * o.w;
  s2 = wave_sum64d(s2);
  if (lane == 0) sqd[row] = s2;
  // pack 4 bf16 -> uint2, swizzled granule write
  uint2 w2;
  w2.x = (unsigned)f2bf(o.x) | ((unsigned)f2bf(o.y) << 16);
  w2.y = (unsigned)f2bf(o.z) | ((unsigned)f2bf(o.w) << 16);
  int T = row >> 6, rl = row & 63, g = lane >> 1, h = lane & 1;
  fb2[((size_t)T * 2048 + rl * 32 + (g ^ (rl & 31))) * 2 + h] = w2;
}

// ---------------- 2. MFMA bf16 candidate Gram + per-row top-8 ----------------
// grid = 512 blocks: (row-block ib 0..127) x (j-split js 0..3).
// Staging is async DMA (global_load_lds width=16): no register round-trip, so
// nothing for the compiler to spill (R4's 208 MB scratch-write pathology).
// Single B buffer: after barrier (c) all MFMA reads of B are done -> issue DMA
// for tile jt+1, overlap with top-k phase, barrier (a) drains vmcnt.
// All LDS read/write patterns identical to R2/R3 (measured 0 bank conflicts).
#define JSPAN (NROWS / NSPLIT)  // 2048

__launch_bounds__(256, 2)
__global__ void k_gram(const uint4* __restrict__ fb, int* __restrict__ candp) {
  __shared__ uint4 Ash4[2048];   // 32 KB bf16, swizzled granules
  __shared__ uint4 Bsh4[2048];   // 32 KB
  __shared__ float Csh[64 * 64]; // 16 KB (reused as merge area)

  const int t  = threadIdx.x;
  const int ib = blockIdx.x >> 2;
  const int js = blockIdx.x & 3;
  const int i0 = ib * 64;
  const int jbase = js * JSPAN;
  const int w = t >> 6, lane = t & 63;

  // ---- async stage A tile + B tile 0 ----
  {
    const uint4* At = fb + (size_t)ib * 2048;
    const uint4* Bt = fb + (size_t)(js * 32) * 2048;
#pragma unroll
    for (int p = 0; p < 8; ++p) {
      int c = w * 8 + p;
      async_cp16(At + c * 64 + lane, &Ash4[c * 64]);
    }
#pragma unroll
    for (int p = 0; p < 8; ++p) {
      int c = w * 8 + p;
      async_cp16(Bt + c * 64 + lane, &Bsh4[c * 64]);
    }
  }

  const int ihalf = w >> 1, jhalf = w & 1;
  const int m15 = lane & 15, quad = lane >> 4;

  float mv[NCAND]; int mi[NCAND];
#pragma unroll
  for (int k = 0; k < NCAND; ++k) { mv[k] = -1e30f; mi[k] = -1; }

  __syncthreads();  // drains vmcnt(0): A and B0 visible

  for (int jt = 0; jt < JSPAN / 64; ++jt) {
    const int j0 = jt * 64;

    f32x4 acc[2][2];
#pragma unroll
    for (int si = 0; si < 2; ++si)
#pragma unroll
      for (int sj = 0; sj < 2; ++sj) acc[si][sj] = (f32x4)(0.f);

#pragma unroll
    for (int kc = 0; kc < 8; ++kc) {
      const int g = kc * 4 + quad;
      bf16x8 av[2], bv[2];
#pragma unroll
      for (int s = 0; s < 2; ++s) {
        int ra = ihalf * 32 + s * 16 + m15;
        av[s] = ((const bf16x8*)Ash4)[ra * 32 + (g ^ (ra & 31))];
        int rb = jhalf * 32 + s * 16 + m15;
        bv[s] = ((const bf16x8*)Bsh4)[rb * 32 + (g ^ (rb & 31))];
      }
      acc[0][0] = __builtin_amdgcn_mfma_f32_16x16x32_bf16(av[0], bv[0], acc[0][0], 0, 0, 0);
      acc[0][1] = __builtin_amdgcn_mfma_f32_16x16x32_bf16(av[0], bv[1], acc[0][1], 0, 0, 0);
      acc[1][0] = __builtin_amdgcn_mfma_f32_16x16x32_bf16(av[1], bv[0], acc[1][0], 0, 0, 0);
      acc[1][1] = __builtin_amdgcn_mfma_f32_16x16x32_bf16(av[1], bv[1], acc[1][1], 0, 0, 0);
    }

    // C -> swizzled LDS. C layout: col=lane&15, row=quad*4+reg.
#pragma unroll
    for (int si = 0; si < 2; ++si)
#pragma unroll
      for (int sj = 0; sj < 2; ++sj)
#pragma unroll
        for (int r = 0; r < 4; ++r) {
          int col = jhalf * 32 + sj * 16 + m15;
          int row = ihalf * 32 + si * 16 + quad * 4 + r;
          int gc = col >> 2, sg = gc ^ (row & 15);
          Csh[row * 64 + sg * 4 + (col & 3)] = acc[si][sj][r];
        }
    __syncthreads();  // (c) C visible; all MFMA reads of B done

    // issue async DMA for next B tile (overlaps with top-k below)
    if (jt + 1 < JSPAN / 64) {
      const uint4* Bt = fb + (size_t)(js * 32 + jt + 1) * 2048;
#pragma unroll
      for (int p = 0; p < 8; ++p) {
        int c = w * 8 + p;
        async_cp16(Bt + c * 64 + lane, &Bsh4[c * 64]);
      }
    }

    // top-8 insert: thread -> (row t>>2, cols (t&3)*16 .. +15)
    {
      int row = t >> 2, q = t & 3;
#pragma unroll
      for (int p = 0; p < 4; ++p) {
        int gc = q * 4 + p, sg = gc ^ (row & 15);
        float4 v = *(const float4*)&Csh[row * 64 + sg * 4];
        int jg = jbase + j0 + gc * 4;
        float vv[4] = {v.x, v.y, v.z, v.w};
#pragma unroll
        for (int s = 0; s < 4; ++s) {
          float val = vv[s];
          if (val > mv[NCAND - 1]) {
            mv[NCAND - 1] = val; mi[NCAND - 1] = jg + s;
#pragma unroll
            for (int k = NCAND - 1; k >= 1; --k) {
              if (mv[k] > mv[k - 1]) {
                float tv = mv[k]; mv[k] = mv[k - 1]; mv[k - 1] = tv;
                int ti = mi[k]; mi[k] = mi[k - 1]; mi[k - 1] = ti;
              }
            }
          }
        }
      }
    }
    __syncthreads();  // (a) top-k reads done; drains vmcnt -> new B visible
  }

  // ---- merge 4 per-thread lists per row -> top-8 per (row, split) ----
  float* mergeV = Csh;                 // [64][32] swizzled
  int*   mergeI = (int*)(Csh + 2048);  // [64][32] swizzled
  {
    int row = t >> 2, q = t & 3;
#pragma unroll
    for (int k = 0; k < NCAND; ++k) {
      int pos = q * NCAND + k;
      mergeV[row * 32 + (pos ^ (row & 31))] = mv[k];
      mergeI[row * 32 + (pos ^ (row & 31))] = mi[k];
    }
  }
  __syncthreads();
  if (t < 64) {
    float fv[NCAND]; int fi[NCAND];
#pragma unroll
    for (int k = 0; k < NCAND; ++k) { fv[k] = -1e30f; fi[k] = -1; }
    for (int s = 0; s < 32; ++s) {
      float v = mergeV[t * 32 + (s ^ (t & 31))];
      int j = mergeI[t * 32 + (s ^ (t & 31))];
      if (v > fv[NCAND - 1]) {
        fv[NCAND - 1] = v; fi[NCAND - 1] = j;
#pragma unroll
        for (int k = NCAND - 1; k >= 1; --k) {
          if (fv[k] > fv[k - 1]) {
            float tv = fv[k]; fv[k] = fv[k - 1]; fv[k - 1] = tv;
            int ti = fi[k]; fi[k] = fi[k - 1]; fi[k - 1] = ti;
          }
        }
      }
    }
#pragma unroll
    for (int k = 0; k < NCAND; ++k)
      candp[(size_t)js * (NROWS * NCAND) + (size_t)(i0 + t) * NCAND + k] = fi[k];
  }
}

// ---------------- 3. fp64 exact refine: 32 candidates -> exact top-5 ----------------
// 4 rows per block (one row per wave). Normalized values recomputed as
// fl(feats/nrm) -- bit-identical to k_normalize's fp32 division.
__global__ void k_refine(const float* __restrict__ feats, const float* __restrict__ nrm,
                         const double* __restrict__ sqd, const int* __restrict__ candp,
                         int* __restrict__ nbr) {
  const int row = blockIdx.x * 4 + (threadIdx.x >> 6);
  const int t = threadIdx.x & 63;
  const int c = t >> 1;        // candidate 0..31
  const int seg = t & 1;       // half of D
  const int split = c >> 3, slot = c & 7;
  int j = candp[(size_t)split * (NROWS * NCAND) + (size_t)row * NCAND + slot];
  const float* fi = feats + (size_t)row * DIM;
  const float* fj = feats + (size_t)j * DIM;
  const float ni = nrm[row], nj = nrm[j];
  double dot = 0.0;
  const int dbase = seg * 128;
#pragma unroll 4
  for (int d = 0; d < 128; ++d) {
    float a = fi[dbase + d] / ni;   // same fp32 div as k_normalize
    float b = fj[dbase + d] / nj;
    dot = fma((double)a, (double)b, dot);
  }
  dot += __shfl_xor(dot, 1, 64);
  double key = sqd[j] - 2.0 * dot;   // == dist2 - sq_i (monotone in dist)
  bool valid = (seg == 0) && (j != row);   // exclude self (== reference idx[:,1:])
  for (int s = 0; s < KNN; ++s) {
    double v = valid ? key : (double)INFINITY;
    int vj = valid ? j : 0x7fffffff;
#pragma unroll
    for (int m = 1; m < 64; m <<= 1) {
      double ov = __shfl_xor(v, m, 64);
      int oj = __shfl_xor(vj, m, 64);
      if (ov < v || (ov == v && oj < vj)) { v = ov; vj = oj; }
    }
    if (valid && vj == j) valid = false;
    if (t == 0) nbr[(size_t)row * 8 + s] = vj;
  }
}

// ---------------- 4. unary + Y0 ----------------
__global__ void k_inity(const float* __restrict__ scores, float* __restrict__ unary,
                        float* __restrict__ Y) {
  int row = blockIdx.x * 4 + (threadIdx.x >> 6);
  int c = threadIdx.x & 63;
  float s = scores[(size_t)row * NCLS + c];
  float u = -logf(s + 1e-10f);
  unary[(size_t)row * NCLS + c] = u;
  float logit = -u;
  float m = wave_max64(logit);
  float e = expf(logit - m);
  float sum = wave_sum64(e);
  Y[(size_t)row * NCLS + c] = e / sum;
}

// ---------------- 5. mean-field iteration + fused convergence check ----------------
// E = sum(u*Y - pw*Y + Y*logY) collapses to -sum_rows lse (LAM == 1).
// R3-proven structure: grid 512, 4 rows per wave, NO launch_bounds (the
// (256,8) cap in R4 forced 64-VGPR spills in the fp64 tail).
__global__ void k_iter(const float* __restrict__ Yin, float* __restrict__ Yout,
                       const float* __restrict__ unary, const int* __restrict__ nbr,
                       IterState* st, double* __restrict__ Epart,
                       int* __restrict__ ctr, int iter) {
  if (st->flag) return;
  const int w = threadIdx.x >> 6;
  const int lane = threadIdx.x & 63;
  const int wid = blockIdx.x * 4 + w;
  double ew = 0.0;
#pragma unroll
  for (int r = 0; r < 4; ++r) {
    int row = wid * 4 + r;
    const int* nb = nbr + (size_t)row * 8;
    float pw = 0.f;
#pragma unroll
    for (int k = 0; k < KNN; ++k) pw += Yin[(size_t)nb[k] * NCLS + lane];
    float logit = pw - unary[(size_t)row * NCLS + lane];
    float m = wave_max64(logit);
    float e = expf(logit - m);
    float sum = wave_sum64(e);
    Yout[(size_t)row * NCLS + lane] = e / sum;
    ew += -(double)(m + logf(sum));
  }
  __shared__ double sE[4];
  __shared__ int isLast;
  if (lane == 0) sE[w] = ew;
  __syncthreads();
  if (threadIdx.x == 0) {
    Epart[blockIdx.x] = (sE[0] + sE[1]) + (sE[2] + sE[3]);
    __threadfence();
    int old = atomicAdd(&ctr[iter], 1);
    isLast = (old == ITER_GRID - 1);
  }
  __syncthreads();
  if (isLast) {
    __threadfence();  // acquire all Epart writes
    __shared__ double sd[256];
    double s = 0.0;
    for (int i = threadIdx.x; i < ITER_GRID; i += 256) s += Epart[i];
    sd[threadIdx.x] = s;
    __syncthreads();
    for (int off = 128; off >= 1; off >>= 1) {
      if (threadIdx.x < off) sd[threadIdx.x] += sd[threadIdx.x + off];
      __syncthreads();
    }
    if (threadIdx.x == 0) {
      double E = sd[0];
      bool conv = (iter > 1) && (fabs(E - st->Eold) <= 1e-8 * fabs(st->Eold));
      st->final_buf = (iter + 1) & 1;  // this iter wrote buf[(iter+1)&1]
      if (conv) st->flag = 1;
      else st->Eold = E;
    }
  }
}

// ---------------- 0/7. state init + final copy ----------------
__global__ void k_init(IterState* st, int* ctr) {
  int t = threadIdx.x;
  if (t < MAXSTEPS) ctr[t] = 0;
  if (t == 255) { st->Eold = (double)INFINITY; st->flag = 0; st->final_buf = 0; }
}
__global__ void k_copy(const float* __restrict__ Ya, const float* __restrict__ Yb,
                       const IterState* __restrict__ st, float* __restrict__ out) {
  const float* src = st->final_buf ? Yb : Ya;
  int i = blockIdx.x * blockDim.x + threadIdx.x;
  ((float4*)out)[i] = ((const float4*)src)[i];
}

extern "C" void kernel_launch(void* const* d_in, const int* in_sizes, int n_in,
                              void* d_out, int out_size, void* d_ws, size_t ws_size,
                              hipStream_t stream) {
  (void)in_sizes; (void)n_in; (void)out_size; (void)ws_size;
  const float* scores = (const float*)d_in[0];
  const float* feats  = (const float*)d_in[1];
  float* out = (float*)d_out;
  char* ws = (char*)d_ws;
  // workspace layout (all 256B-aligned); total ~11.9 MB
  uint4*  fb    = (uint4*)(ws + 0);          //  4 MB pre-swizzled bf16 tiles
  float*  Ya    = (float*)(ws + 4194304);    //  2 MB
  float*  Yb    = (float*)(ws + 6291456);    //  2 MB
  float*  unary = (float*)(ws + 8388608);    //  2 MB
  double* sqd   = (double*)(ws + 10485760);  // 64 KB
  float*  nrm   = (float*)(ws + 10551296);   // 32 KB
  int*    candp = (int*)(ws + 10584064);     //  1 MB (4 splits x 8192 x 8)
  int*    nbr   = (int*)(ws + 11632640);     // 256 KB
  double* Epart = (double*)(ws + 11894784);  //  4 KB
  int*    ctr   = (int*)(ws + 11898880);     // 512 B
  IterState* st = (IterState*)(ws + 11899392);

  k_init<<<1, 256, 0, stream>>>(st, ctr);
  k_normalize<<<NROWS / 4, 256, 0, stream>>>(feats, (uint2*)fb, nrm, sqd);
  k_gram<<<(NROWS / 64) * NSPLIT, 256, 0, stream>>>(fb, candp);
  k_refine<<<NROWS / 4, 256, 0, stream>>>(feats, nrm, sqd, candp, nbr);
  k_inity<<<NROWS / 4, 256, 0, stream>>>(scores, unary, Ya);
  for (int k = 0; k < MAXSTEPS; ++k) {
    const float* yin = (k & 1) ? Yb : Ya;
    float* yout = (k & 1) ? Ya : Yb;
    k_iter<<<ITER_GRID, 256, 0, stream>>>(yin, yout, unary, nbr, st, Epart, ctr, k);
  }
  k_copy<<<512, 256, 0, stream>>>(Ya, Yb, st, out);
}

// Round 6
// 281.517 us; speedup vs baseline: 3.0665x; 2.0921x over previous
//
#include <hip/hip_runtime.h>
#include <math.h>

#define NROWS 8192
#define DIM   256
#define NCLS  64
#define KNN   5
#define NCAND 8      // per (row, j-split)
#define NSPLIT 4
#define MAXSTEPS 100
#define PBLK 256     // persistent-solver blocks: 1 per CU -> co-residency guaranteed

struct GS {
  double Eold;
  double Epart[PBLK];
  int count; int gen; int flag; int _pad;
};

typedef __attribute__((ext_vector_type(8))) short bf16x8;
typedef __attribute__((ext_vector_type(4))) float f32x4;

typedef __attribute__((address_space(1))) unsigned int glb_u32_t;
typedef __attribute__((address_space(3))) unsigned int lds_u32_t;
// async global->LDS DMA, 16 B/lane; LDS dest = wave-uniform base + lane*16
__device__ __forceinline__ void async_cp16(const uint4* g, uint4* l) {
  __builtin_amdgcn_global_load_lds((const glb_u32_t*)(const unsigned int*)g,
                                   (lds_u32_t*)(unsigned int*)l, 16, 0, 0);
}

// ---------------- wave (64-lane) reductions ----------------
__device__ __forceinline__ float wave_sum64(float v) {
#pragma unroll
  for (int m = 32; m >= 1; m >>= 1) v += __shfl_xor(v, m, 64);
  return v;
}
__device__ __forceinline__ double wave_sum64d(double v) {
#pragma unroll
  for (int m = 32; m >= 1; m >>= 1) v += __shfl_xor(v, m, 64);
  return v;
}

__device__ __forceinline__ unsigned short f2bf(float x) {  // RNE bf16
  unsigned u = __float_as_uint(x);
  u += 0x7FFFu + ((u >> 16) & 1u);
  return (unsigned short)(u >> 16);
}

// ---------------- 1. normalize: pre-swizzled bf16 tiles + nrm + sqd ----------------
// fb layout (uint4 granules = 8 bf16 dims): row r -> tile T=r>>6, local row
// rl=r&63, granule g: fb_uint4[T*2048 + rl*32 + (g ^ (rl&31))].
__global__ void k_normalize(const float* __restrict__ feats, uint2* __restrict__ fb2,
                            float* __restrict__ nrm, double* __restrict__ sqd) {
  int row  = blockIdx.x * 4 + (threadIdx.x >> 6);
  int lane = threadIdx.x & 63;
  float4 v = ((const float4*)(feats + (size_t)row * DIM))[lane];
  double ss = (double)v.x * v.x + (double)v.y * v.y + (double)v.z * v.z + (double)v.w * v.w;
  ss = wave_sum64d(ss);
  float nr = fmaxf((float)sqrt(ss), 1e-12f);
  if (lane == 0) nrm[row] = nr;
  float4 o;  // exact fp32 division (k_refine recomputes bit-identically)
  o.x = v.x / nr; o.y = v.y / nr; o.z = v.z / nr; o.w = v.w / nr;
  double s2 = (double)o.x * o.x + (double)o.y * o.y + (double)o.z * o.z + (double)o.w * o.w;
  s2 = wave_sum64d(s2);
  if (lane == 0) sqd[row] = s2;
  uint2 w2;
  w2.x = (unsigned)f2bf(o.x) | ((unsigned)f2bf(o.y) << 16);
  w2.y = (unsigned)f2bf(o.z) | ((unsigned)f2bf(o.w) << 16);
  int T = row >> 6, rl = row & 63, g = lane >> 1, h = lane & 1;
  fb2[((size_t)T * 2048 + rl * 32 + (g ^ (rl & 31))) * 2 + h] = w2;
}

// ---------------- 2. MFMA bf16 candidate Gram + per-row top-8 ----------------
// grid 512: (row-block ib 0..127) x (j-split js 0..3).
// A-quadrant fragments cached in registers (loaded once from LDS buf1, which
// then becomes B's second buffer). Double-buffered B via async DMA -> ONE
// barrier per j-tile. Top-k is wave-local (per-wave Csh quadrant; same-wave
// LDS write->read needs no barrier) and branchy: group-max-of-4 vs a
// conservative threshold skips the insert body. Keys are sign-transformed
// uint32 with low 11 bits = column index (candidate SELECTION only; the fp64
// refine recomputes exact order).
#define JSPAN (NROWS / NSPLIT)  // 2048
#define GTILES (JSPAN / 64)     // 32

__launch_bounds__(256, 2)
__global__ void k_gram(const uint4* __restrict__ fb, int* __restrict__ candp) {
  __shared__ uint4 Bsh4[2][2048];   // 64 KB; buf1 stages A first
  __shared__ float Csh[4096];       // 16 KB: per-wave 1024-float C quadrants / merge

  const int t  = threadIdx.x;
  const int ib = blockIdx.x >> 2;
  const int js = blockIdx.x & 3;
  const int i0 = ib * 64;
  const int jbase = js * JSPAN;
  const int w = t >> 6, lane = t & 63;

  // DMA: A -> buf1, B tile0 -> buf0
  {
    const uint4* At = fb + (size_t)ib * 2048;
    const uint4* Bt = fb + (size_t)(js * 32) * 2048;
#pragma unroll
    for (int p = 0; p < 8; ++p) {
      int c = w * 8 + p;
      async_cp16(At + c * 64 + lane, &Bsh4[1][c * 64]);
      async_cp16(Bt + c * 64 + lane, &Bsh4[0][c * 64]);
    }
  }
  const int ihalf = w >> 1, jhalf = w & 1;
  const int m15 = lane & 15, quad = lane >> 4;

  __syncthreads();  // drain DMA: A + B0 visible

  // A-quadrant fragments -> registers (rows ihalf*32 .. +31, all K)
  bf16x8 areg[2][8];
#pragma unroll
  for (int s = 0; s < 2; ++s) {
    int ra = ihalf * 32 + s * 16 + m15;
#pragma unroll
    for (int kc = 0; kc < 8; ++kc)
      areg[s][kc] = ((const bf16x8*)Bsh4[1])[ra * 32 + ((kc * 4 + quad) ^ (ra & 31))];
  }
  __syncthreads();  // all waves done reading A from buf1 -> buf1 reusable

  unsigned mk[NCAND];
#pragma unroll
  for (int k = 0; k < NCAND; ++k) mk[k] = 0u;
  float thr = -1e30f;

  const int trow = lane >> 1;   // top-k: local row 0..31 of wave quadrant
  const int thalf = lane & 1;   // 16-col half
  float* Csw = Csh + w * 1024;

  for (int jt = 0; jt < GTILES; ++jt) {
    const int cbuf = jt & 1;
    if (jt > 0) __syncthreads();  // waves done with buf[1-cbuf]; DMA->buf[cbuf] drained
    if (jt + 1 < GTILES) {
      const uint4* Bt = fb + (size_t)(js * 32 + jt + 1) * 2048;
#pragma unroll
      for (int p = 0; p < 8; ++p) {
        int c = w * 8 + p;
        async_cp16(Bt + c * 64 + lane, &Bsh4[1 - cbuf][c * 64]);
      }
    }

    f32x4 acc[2][2];
#pragma unroll
    for (int si = 0; si < 2; ++si)
#pragma unroll
      for (int sj = 0; sj < 2; ++sj) acc[si][sj] = (f32x4)(0.f);

#pragma unroll
    for (int kc = 0; kc < 8; ++kc) {
      bf16x8 bv[2];
#pragma unroll
      for (int s = 0; s < 2; ++s) {
        int rb = jhalf * 32 + s * 16 + m15;
        bv[s] = ((const bf16x8*)Bsh4[cbuf])[rb * 32 + ((kc * 4 + quad) ^ (rb & 31))];
      }
      acc[0][0] = __builtin_amdgcn_mfma_f32_16x16x32_bf16(areg[0][kc], bv[0], acc[0][0], 0, 0, 0);
      acc[0][1] = __builtin_amdgcn_mfma_f32_16x16x32_bf16(areg[0][kc], bv[1], acc[0][1], 0, 0, 0);
      acc[1][0] = __builtin_amdgcn_mfma_f32_16x16x32_bf16(areg[1][kc], bv[0], acc[1][0], 0, 0, 0);
      acc[1][1] = __builtin_amdgcn_mfma_f32_16x16x32_bf16(areg[1][kc], bv[1], acc[1][1], 0, 0, 0);
    }

    // C scatter -> wave-local quadrant (32x32). C layout: col=lane&15, row=quad*4+r.
    // Granule swizzle (gc ^ (lr&7)): writes 2-way (free), b128 reads conflict-free.
#pragma unroll
    for (int si = 0; si < 2; ++si)
#pragma unroll
      for (int sj = 0; sj < 2; ++sj)
#pragma unroll
        for (int r = 0; r < 4; ++r) {
          int lr = si * 16 + quad * 4 + r;
          int lc = sj * 16 + m15;
          int gc = lc >> 2;
          Csw[lr * 32 + ((gc ^ (lr & 7)) << 2) + (lc & 3)] = acc[si][sj][r];
        }

    // wave-local top-8: lane scans (row trow, cols thalf*16..+15) of quadrant
    {
      int cb0 = jt * 64 + jhalf * 32;  // split-local column base (11-bit idx)
#pragma unroll
      for (int p = 0; p < 4; ++p) {
        int gc = thalf * 4 + p;
        float4 v = *(const float4*)&Csw[trow * 32 + ((gc ^ (trow & 7)) << 2)];
        float g4 = fmaxf(fmaxf(v.x, v.y), fmaxf(v.z, v.w));
        if (g4 > thr) {
          int cbase = cb0 + gc * 4;
          float vv[4] = {v.x, v.y, v.z, v.w};
#pragma unroll
          for (int e = 0; e < 4; ++e) {
            unsigned ub = __float_as_uint(vv[e]);
            unsigned key = ((ub ^ (unsigned)(((int)ub >> 31) | 0x80000000)) & ~2047u)
                           | (unsigned)(cbase + e);
            if (key > mk[NCAND - 1]) {
              mk[NCAND - 1] = key;
#pragma unroll
              for (int q = NCAND - 1; q >= 1; --q)
                if (mk[q] > mk[q - 1]) { unsigned tm = mk[q]; mk[q] = mk[q - 1]; mk[q - 1] = tm; }
            }
          }
          unsigned kb = mk[NCAND - 1] & ~2047u;
          if (kb) {  // conservative float threshold from 8th-best key
            unsigned xm = 0x80000000u | ~(unsigned)((int)kb >> 31);
            thr = __uint_as_float(kb ^ xm);
          }
        }
      }
    }
  }

  // ---- merge 4 per-thread lists per row -> top-8 per (row, split) ----
  __syncthreads();  // all waves done with their Csw quadrants
  unsigned* mergeK = (unsigned*)Csh;  // [64][33] padded stride (2-way writes, cf reads)
  {
    int grow = ihalf * 32 + trow;
    int q = jhalf * 2 + thalf;
#pragma unroll
    for (int k = 0; k < NCAND; ++k) mergeK[grow * 33 + q * 8 + k] = mk[k];
  }
  __syncthreads();
  if (t < 64) {
    unsigned fk[NCAND];
#pragma unroll
    for (int k = 0; k < NCAND; ++k) fk[k] = 0u;
    for (int s = 0; s < 32; ++s) {
      unsigned kk = mergeK[t * 33 + s];
      if (kk > fk[NCAND - 1]) {
        fk[NCAND - 1] = kk;
#pragma unroll
        for (int q = NCAND - 1; q >= 1; --q)
          if (fk[q] > fk[q - 1]) { unsigned tm = fk[q]; fk[q] = fk[q - 1]; fk[q - 1] = tm; }
      }
    }
#pragma unroll
    for (int k = 0; k < NCAND; ++k)
      candp[(size_t)js * (NROWS * NCAND) + (size_t)(i0 + t) * NCAND + k] =
          jbase + (int)(fk[k] & 2047u);
  }
}

// ---------------- 3. fp64 exact refine: 32 candidates -> exact top-5 ----------------
__global__ void k_refine(const float* __restrict__ feats, const float* __restrict__ nrm,
                         const double* __restrict__ sqd, const int* __restrict__ candp,
                         int* __restrict__ nbr) {
  const int row = blockIdx.x * 4 + (threadIdx.x >> 6);
  const int t = threadIdx.x & 63;
  const int c = t >> 1;        // candidate 0..31
  const int seg = t & 1;       // half of D
  const int split = c >> 3, slot = c & 7;
  int j = candp[(size_t)split * (NROWS * NCAND) + (size_t)row * NCAND + slot];
  const float* fi = feats + (size_t)row * DIM;
  const float* fj = feats + (size_t)j * DIM;
  const float ni = nrm[row], nj = nrm[j];
  double dot = 0.0;
  const int dbase = seg * 128;
#pragma unroll 4
  for (int d = 0; d < 128; ++d) {
    float a = fi[dbase + d] / ni;
    float b = fj[dbase + d] / nj;
    dot = fma((double)a, (double)b, dot);
  }
  dot += __shfl_xor(dot, 1, 64);
  double key = sqd[j] - 2.0 * dot;
  bool valid = (seg == 0) && (j != row);
  for (int s = 0; s < KNN; ++s) {
    double v = valid ? key : (double)INFINITY;
    int vj = valid ? j : 0x7fffffff;
#pragma unroll
    for (int m = 1; m < 64; m <<= 1) {
      double ov = __shfl_xor(v, m, 64);
      int oj = __shfl_xor(vj, m, 64);
      if (ov < v || (ov == v && oj < vj)) { v = ov; vj = oj; }
    }
    if (valid && vj == j) valid = false;
    if (t == 0) nbr[(size_t)row * 8 + s] = vj;
  }
}

// ---------------- 4. persistent solver: Y0 + all iterations + out ----------------
// 256 blocks (1/CU), 32 rows/block (8 rows/wave, lane=class). Unary + own Y
// rows in registers; neighbors in LDS. Grid barrier = proven fence+atomic
// last-block pattern with a generation counter. Softmax without max-sub
// (logits in [-23,5] -> exp in [1e-10,148], safe). E = -sum lse (LAM=1).
__global__ void k_solve(const float* __restrict__ scores,
                        const int* __restrict__ nbr,
                        float* __restrict__ Ya, float* __restrict__ Yb,
                        float* __restrict__ out, GS* __restrict__ gs) {
  const int b = blockIdx.x;
  const int w = threadIdx.x >> 6, lane = threadIdx.x & 63;
  const int row0 = b * 32 + w * 8;
  __shared__ int nbl[32][5];
  __shared__ double sE[4];
  __shared__ double sd[256];
  __shared__ int isLast, sflag;

  for (int i = threadIdx.x; i < 32 * 5; i += 256)
    nbl[i / 5][i % 5] = nbr[(size_t)(b * 32 + i / 5) * 8 + (i % 5)];

  float u[8], y[8];
#pragma unroll
  for (int r = 0; r < 8; ++r)
    u[r] = -logf(scores[(size_t)(row0 + r) * NCLS + lane] + 1e-10f);
#pragma unroll
  for (int r = 0; r < 8; ++r) {
    float e = expf(-u[r]);
    float sum = wave_sum64(e);
    y[r] = e / sum;
    Ya[(size_t)(row0 + r) * NCLS + lane] = y[r];
  }
  __syncthreads();  // nbl ready; own Y0 stores complete (vmcnt drained)

  int mygen = 1;
  // grid barrier: publish Y0
  if (threadIdx.x == 0) {
    __threadfence();
    int old = atomicAdd(&gs->count, 1);
    if (old == PBLK - 1) { gs->count = 0; __threadfence(); atomicAdd(&gs->gen, 1); }
    while (__hip_atomic_load(&gs->gen, __ATOMIC_ACQUIRE, __HIP_MEMORY_SCOPE_AGENT) < mygen)
      __builtin_amdgcn_s_sleep(8);
    __threadfence();
  }
  __syncthreads();
  ++mygen;

  for (int iter = 0; iter < MAXSTEPS; ++iter) {
    const float* __restrict__ Yin = (iter & 1) ? Yb : Ya;
    float* __restrict__ Yout = (iter & 1) ? Ya : Yb;
    double ew = 0.0;
#pragma unroll
    for (int r = 0; r < 8; ++r) {
      const int lr = w * 8 + r;
      float pw = 0.f;
#pragma unroll
      for (int k = 0; k < KNN; ++k)
        pw += Yin[(size_t)nbl[lr][k] * NCLS + lane];
      float e = expf(pw - u[r]);
      float sum = wave_sum64(e);
      y[r] = e / sum;
      Yout[(size_t)(row0 + r) * NCLS + lane] = y[r];
      ew += -(double)logf(sum);
    }
    if (lane == 0) sE[w] = ew;
    __syncthreads();  // sE ready + all Y stores drained to L2
    if (threadIdx.x == 0) {
      gs->Epart[b] = (sE[0] + sE[1]) + (sE[2] + sE[3]);
      __threadfence();  // release Epart + this block's Y (L2 writeback)
      int old = atomicAdd(&gs->count, 1);
      isLast = (old == PBLK - 1) ? 1 : 0;
    }
    __syncthreads();
    if (isLast) {  // whole last block: parallel E reduction
      __threadfence();  // acquire all Epart
      sd[threadIdx.x] = gs->Epart[threadIdx.x];
      __syncthreads();
      for (int off = 128; off >= 1; off >>= 1) {
        if (threadIdx.x < off) sd[threadIdx.x] += sd[threadIdx.x + off];
        __syncthreads();
      }
      if (threadIdx.x == 0) {
        double E = sd[0];
        int conv = (iter > 1) && (fabs(E - gs->Eold) <= 1e-8 * fabs(gs->Eold));
        gs->flag = conv;
        if (!conv) gs->Eold = E;
        gs->count = 0;
        __threadfence();
        atomicAdd(&gs->gen, 1);  // release epoch
      }
    }
    if (threadIdx.x == 0) {
      while (__hip_atomic_load(&gs->gen, __ATOMIC_ACQUIRE, __HIP_MEMORY_SCOPE_AGENT) < mygen)
        __builtin_amdgcn_s_sleep(8);
      __threadfence();  // acquire other blocks' Y + flag
      sflag = gs->flag;
    }
    __syncthreads();
    ++mygen;
    if (sflag) break;  // uniform across grid
  }

  // y regs hold the final iteration's values for this block's rows
#pragma unroll
  for (int r = 0; r < 8; ++r)
    out[(size_t)(row0 + r) * NCLS + lane] = y[r];
}

// ---------------- 0. state init ----------------
__global__ void k_init(GS* gs) {
  if (threadIdx.x == 0) {
    gs->Eold = (double)INFINITY;
    gs->count = 0; gs->gen = 0; gs->flag = 0;
  }
}

extern "C" void kernel_launch(void* const* d_in, const int* in_sizes, int n_in,
                              void* d_out, int out_size, void* d_ws, size_t ws_size,
                              hipStream_t stream) {
  (void)in_sizes; (void)n_in; (void)out_size; (void)ws_size;
  const float* scores = (const float*)d_in[0];
  const float* feats  = (const float*)d_in[1];
  float* out = (float*)d_out;
  char* ws = (char*)d_ws;
  // workspace layout (256B-aligned); total ~9.8 MB
  uint4*  fb    = (uint4*)(ws + 0);          //  4 MB pre-swizzled bf16 tiles
  float*  Ya    = (float*)(ws + 4194304);    //  2 MB
  float*  Yb    = (float*)(ws + 6291456);    //  2 MB
  double* sqd   = (double*)(ws + 8388608);   // 64 KB
  float*  nrm   = (float*)(ws + 8454144);    // 32 KB
  int*    candp = (int*)(ws + 8486912);      //  1 MB (4 splits x 8192 x 8)
  int*    nbr   = (int*)(ws + 9535488);      // 256 KB
  GS*     gs    = (GS*)(ws + 9791744);       // ~2.1 KB

  k_init<<<1, 64, 0, stream>>>(gs);
  k_normalize<<<NROWS / 4, 256, 0, stream>>>(feats, (uint2*)fb, nrm, sqd);
  k_gram<<<(NROWS / 64) * NSPLIT, 256, 0, stream>>>(fb, candp);
  k_refine<<<NROWS / 4, 256, 0, stream>>>(feats, nrm, sqd, candp, nbr);
  k_solve<<<PBLK, 256, 0, stream>>>(scores, nbr, Ya, Yb, out, gs);
}

// Round 7
// 281.138 us; speedup vs baseline: 3.0706x; 1.0013x over previous
//
#include <hip/hip_runtime.h>
#include <math.h>

#define NROWS 8192
#define DIM   256
#define NCLS  64
#define KNN   5
#define NCAND 8      // per (row, j-split)
#define NSPLIT 4
#define MAXSTEPS 100
#define PBLK 256     // persistent-solver blocks: 1 per CU -> co-residency guaranteed

struct GS {
  double Eold;
  double Epart[PBLK];
  int count; int gen; int flag; int _pad;
};

typedef __attribute__((ext_vector_type(8))) short bf16x8;
typedef __attribute__((ext_vector_type(4))) float f32x4;

typedef __attribute__((address_space(1))) unsigned int glb_u32_t;
typedef __attribute__((address_space(3))) unsigned int lds_u32_t;
// async global->LDS DMA, 16 B/lane; LDS dest = wave-uniform base + lane*16
__device__ __forceinline__ void async_cp16(const uint4* g, uint4* l) {
  __builtin_amdgcn_global_load_lds((const glb_u32_t*)(const unsigned int*)g,
                                   (lds_u32_t*)(unsigned int*)l, 16, 0, 0);
}

// ---------------- wave (64-lane) reductions ----------------
__device__ __forceinline__ float wave_sum64(float v) {
#pragma unroll
  for (int m = 32; m >= 1; m >>= 1) v += __shfl_xor(v, m, 64);
  return v;
}
__device__ __forceinline__ double wave_sum64d(double v) {
#pragma unroll
  for (int m = 32; m >= 1; m >>= 1) v += __shfl_xor(v, m, 64);
  return v;
}

__device__ __forceinline__ unsigned short f2bf(float x) {  // RNE bf16
  unsigned u = __float_as_uint(x);
  u += 0x7FFFu + ((u >> 16) & 1u);
  return (unsigned short)(u >> 16);
}

// ---------------- 1. normalize: pre-swizzled bf16 tiles + nrm + sqd ----------------
// fb layout (uint4 granules = 8 bf16 dims): row r -> tile T=r>>6, local row
// rl=r&63, granule g: fb_uint4[T*2048 + rl*32 + (g ^ (rl&31))].
__global__ void k_normalize(const float* __restrict__ feats, uint2* __restrict__ fb2,
                            float* __restrict__ nrm, double* __restrict__ sqd) {
  int row  = blockIdx.x * 4 + (threadIdx.x >> 6);
  int lane = threadIdx.x & 63;
  float4 v = ((const float4*)(feats + (size_t)row * DIM))[lane];
  double ss = (double)v.x * v.x + (double)v.y * v.y + (double)v.z * v.z + (double)v.w * v.w;
  ss = wave_sum64d(ss);
  float nr = fmaxf((float)sqrt(ss), 1e-12f);
  if (lane == 0) nrm[row] = nr;
  float4 o;  // exact fp32 division (k_refine recomputes bit-identically)
  o.x = v.x / nr; o.y = v.y / nr; o.z = v.z / nr; o.w = v.w / nr;
  double s2 = (double)o.x * o.x + (double)o.y * o.y + (double)o.z * o.z + (double)o.w * o.w;
  s2 = wave_sum64d(s2);
  if (lane == 0) sqd[row] = s2;
  uint2 w2;
  w2.x = (unsigned)f2bf(o.x) | ((unsigned)f2bf(o.y) << 16);
  w2.y = (unsigned)f2bf(o.z) | ((unsigned)f2bf(o.w) << 16);
  int T = row >> 6, rl = row & 63, g = lane >> 1, h = lane & 1;
  fb2[((size_t)T * 2048 + rl * 32 + (g ^ (rl & 31))) * 2 + h] = w2;
}

// ---------------- 2. MFMA bf16 candidate Gram + per-row top-8 ----------------
// grid 512: (row-block ib 0..127) x (j-split js 0..3).
// A-quadrant fragments in registers; double-buffered B via async DMA -> one
// barrier per j-tile. Wave-local branchy top-k over a per-wave C quadrant.
// C swizzle key = (lr>>1)&6 (== quad*2): constant across each acc float4's 4
// rows, so the scatter is 4 stores at +0/+128/+256/+384 B from one base ->
// compiler pairs them into 2x ds_write2_b32. Banks: writes 2 lanes/bank
// (free), scan b128 reads balanced.
#define JSPAN (NROWS / NSPLIT)  // 2048
#define GTILES (JSPAN / 64)     // 32

__launch_bounds__(256, 2)
__global__ void k_gram(const uint4* __restrict__ fb, int* __restrict__ candp) {
  __shared__ uint4 Bsh4[2][2048];   // 64 KB; buf1 stages A first
  __shared__ float Csh[4096];       // 16 KB: per-wave 1024-float C quadrants / merge

  const int t  = threadIdx.x;
  const int ib = blockIdx.x >> 2;
  const int js = blockIdx.x & 3;
  const int i0 = ib * 64;
  const int jbase = js * JSPAN;
  const int w = t >> 6, lane = t & 63;

  // DMA: A -> buf1, B tile0 -> buf0
  {
    const uint4* At = fb + (size_t)ib * 2048;
    const uint4* Bt = fb + (size_t)(js * 32) * 2048;
#pragma unroll
    for (int p = 0; p < 8; ++p) {
      int c = w * 8 + p;
      async_cp16(At + c * 64 + lane, &Bsh4[1][c * 64]);
      async_cp16(Bt + c * 64 + lane, &Bsh4[0][c * 64]);
    }
  }
  const int ihalf = w >> 1, jhalf = w & 1;
  const int m15 = lane & 15, quad = lane >> 4;

  __syncthreads();  // drain DMA: A + B0 visible

  // A-quadrant fragments -> registers (rows ihalf*32 .. +31, all K)
  bf16x8 areg[2][8];
#pragma unroll
  for (int s = 0; s < 2; ++s) {
    int ra = ihalf * 32 + s * 16 + m15;
#pragma unroll
    for (int kc = 0; kc < 8; ++kc)
      areg[s][kc] = ((const bf16x8*)Bsh4[1])[ra * 32 + ((kc * 4 + quad) ^ (ra & 31))];
  }
  __syncthreads();  // all waves done reading A from buf1 -> buf1 reusable

  unsigned mk[NCAND];
#pragma unroll
  for (int k = 0; k < NCAND; ++k) mk[k] = 0u;
  float thr = -1e30f;

  const int trow = lane >> 1;   // top-k: local row 0..31 of wave quadrant
  const int thalf = lane & 1;   // 16-col half
  float* Csw = Csh + w * 1024;

  for (int jt = 0; jt < GTILES; ++jt) {
    const int cbuf = jt & 1;
    if (jt > 0) __syncthreads();  // waves done with buf[1-cbuf]; DMA->buf[cbuf] drained
    if (jt + 1 < GTILES) {
      const uint4* Bt = fb + (size_t)(js * 32 + jt + 1) * 2048;
#pragma unroll
      for (int p = 0; p < 8; ++p) {
        int c = w * 8 + p;
        async_cp16(Bt + c * 64 + lane, &Bsh4[1 - cbuf][c * 64]);
      }
    }

    f32x4 acc[2][2];
#pragma unroll
    for (int si = 0; si < 2; ++si)
#pragma unroll
      for (int sj = 0; sj < 2; ++sj) acc[si][sj] = (f32x4)(0.f);

#pragma unroll
    for (int kc = 0; kc < 8; ++kc) {
      bf16x8 bv[2];
#pragma unroll
      for (int s = 0; s < 2; ++s) {
        int rb = jhalf * 32 + s * 16 + m15;
        bv[s] = ((const bf16x8*)Bsh4[cbuf])[rb * 32 + ((kc * 4 + quad) ^ (rb & 31))];
      }
      acc[0][0] = __builtin_amdgcn_mfma_f32_16x16x32_bf16(areg[0][kc], bv[0], acc[0][0], 0, 0, 0);
      acc[0][1] = __builtin_amdgcn_mfma_f32_16x16x32_bf16(areg[0][kc], bv[1], acc[0][1], 0, 0, 0);
      acc[1][0] = __builtin_amdgcn_mfma_f32_16x16x32_bf16(areg[1][kc], bv[0], acc[1][0], 0, 0, 0);
      acc[1][1] = __builtin_amdgcn_mfma_f32_16x16x32_bf16(areg[1][kc], bv[1], acc[1][1], 0, 0, 0);
    }

    // C scatter -> wave-local quadrant (32x32). C layout: col=lane&15, row=quad*4+r.
    // All 4 rows of each acc float4 share swizzle key (lr>>1)&6 == quad*2 ->
    // stores at base +0/+128/+256/+384 B (pairable into ds_write2_b32).
#pragma unroll
    for (int si = 0; si < 2; ++si)
#pragma unroll
      for (int sj = 0; sj < 2; ++sj) {
        int lr0 = si * 16 + quad * 4;
        int key = quad * 2;                 // == (lr0>>1)&6
        int lc = sj * 16 + m15;
        int gc = lc >> 2;
        int base = lr0 * 32 + ((gc ^ key) << 2) + (lc & 3);
#pragma unroll
        for (int r = 0; r < 4; ++r)
          Csw[base + r * 32] = acc[si][sj][r];
      }

    // wave-local top-8: lane scans (row trow, cols thalf*16..+15) of quadrant
    {
      int cb0 = jt * 64 + jhalf * 32;  // split-local column base (11-bit idx)
      int skey = (trow >> 1) & 6;      // matches write key for row trow
#pragma unroll
      for (int p = 0; p < 4; ++p) {
        int gc = thalf * 4 + p;
        float4 v = *(const float4*)&Csw[trow * 32 + ((gc ^ skey) << 2)];
        float g4 = fmaxf(fmaxf(v.x, v.y), fmaxf(v.z, v.w));
        if (g4 > thr) {
          int cbase = cb0 + gc * 4;
          float vv[4] = {v.x, v.y, v.z, v.w};
#pragma unroll
          for (int e = 0; e < 4; ++e) {
            unsigned ub = __float_as_uint(vv[e]);
            unsigned key = ((ub ^ (unsigned)(((int)ub >> 31) | 0x80000000)) & ~2047u)
                           | (unsigned)(cbase + e);
            if (key > mk[NCAND - 1]) {
              mk[NCAND - 1] = key;
#pragma unroll
              for (int q = NCAND - 1; q >= 1; --q)
                if (mk[q] > mk[q - 1]) { unsigned tm = mk[q]; mk[q] = mk[q - 1]; mk[q - 1] = tm; }
            }
          }
          unsigned kb = mk[NCAND - 1] & ~2047u;
          if (kb) {  // conservative float threshold from 8th-best key
            unsigned xm = 0x80000000u | ~(unsigned)((int)kb >> 31);
            thr = __uint_as_float(kb ^ xm);
          }
        }
      }
    }
  }

  // ---- merge 4 per-thread lists per row -> top-8 per (row, split) ----
  __syncthreads();  // all waves done with their Csw quadrants
  unsigned* mergeK = (unsigned*)Csh;  // [64][33] padded stride
  {
    int grow = ihalf * 32 + trow;
    int q = jhalf * 2 + thalf;
#pragma unroll
    for (int k = 0; k < NCAND; ++k) mergeK[grow * 33 + q * 8 + k] = mk[k];
  }
  __syncthreads();
  if (t < 64) {
    unsigned fk[NCAND];
#pragma unroll
    for (int k = 0; k < NCAND; ++k) fk[k] = 0u;
    for (int s = 0; s < 32; ++s) {
      unsigned kk = mergeK[t * 33 + s];
      if (kk > fk[NCAND - 1]) {
        fk[NCAND - 1] = kk;
#pragma unroll
        for (int q = NCAND - 1; q >= 1; --q)
          if (fk[q] > fk[q - 1]) { unsigned tm = fk[q]; fk[q] = fk[q - 1]; fk[q - 1] = tm; }
      }
    }
#pragma unroll
    for (int k = 0; k < NCAND; ++k)
      candp[(size_t)js * (NROWS * NCAND) + (size_t)(i0 + t) * NCAND + k] =
          jbase + (int)(fk[k] & 2047u);
  }
}

// ---------------- 3. fp64 exact refine: 32 candidates -> exact top-5 ----------------
__global__ void k_refine(const float* __restrict__ feats, const float* __restrict__ nrm,
                         const double* __restrict__ sqd, const int* __restrict__ candp,
                         int* __restrict__ nbr) {
  const int row = blockIdx.x * 4 + (threadIdx.x >> 6);
  const int t = threadIdx.x & 63;
  const int c = t >> 1;        // candidate 0..31
  const int seg = t & 1;       // half of D
  const int split = c >> 3, slot = c & 7;
  int j = candp[(size_t)split * (NROWS * NCAND) + (size_t)row * NCAND + slot];
  const float* fi = feats + (size_t)row * DIM;
  const float* fj = feats + (size_t)j * DIM;
  const float ni = nrm[row], nj = nrm[j];
  double dot = 0.0;
  const int dbase = seg * 128;
#pragma unroll 4
  for (int d = 0; d < 128; ++d) {
    float a = fi[dbase + d] / ni;
    float b = fj[dbase + d] / nj;
    dot = fma((double)a, (double)b, dot);
  }
  dot += __shfl_xor(dot, 1, 64);
  double key = sqd[j] - 2.0 * dot;
  bool valid = (seg == 0) && (j != row);
  for (int s = 0; s < KNN; ++s) {
    double v = valid ? key : (double)INFINITY;
    int vj = valid ? j : 0x7fffffff;
#pragma unroll
    for (int m = 1; m < 64; m <<= 1) {
      double ov = __shfl_xor(v, m, 64);
      int oj = __shfl_xor(vj, m, 64);
      if (ov < v || (ov == v && oj < vj)) { v = ov; vj = oj; }
    }
    if (valid && vj == j) valid = false;
    if (t == 0) nbr[(size_t)row * 8 + s] = vj;
  }
}

// ---------------- 4. persistent solver: Y0 + all iterations + out ----------------
// 256 blocks (1/CU) x 512 threads (8 waves, 4 rows/wave, lane=class) -> 8
// waves/CU of latency hiding for the gather phase. Grid barrier = proven
// fence+atomic generation pattern. Softmax without max-sub (logits in
// [-23,5], overflow-impossible). E = -sum lse (LAM=1). Last-block E
// reduction done by one wave (no block-wide tree).
__global__ void k_solve(const float* __restrict__ scores,
                        const int* __restrict__ nbr,
                        float* __restrict__ Ya, float* __restrict__ Yb,
                        float* __restrict__ out, GS* __restrict__ gs) {
  const int b = blockIdx.x;
  const int w = threadIdx.x >> 6, lane = threadIdx.x & 63;
  const int row0 = b * 32 + w * 4;
  __shared__ int nbl[32][5];
  __shared__ double sE[8];
  __shared__ int isLast, sflag;

  if (threadIdx.x < 160)
    nbl[threadIdx.x / 5][threadIdx.x % 5] =
        nbr[(size_t)(b * 32 + threadIdx.x / 5) * 8 + (threadIdx.x % 5)];

  float u[4], y[4];
#pragma unroll
  for (int r = 0; r < 4; ++r)
    u[r] = -logf(scores[(size_t)(row0 + r) * NCLS + lane] + 1e-10f);
#pragma unroll
  for (int r = 0; r < 4; ++r) {
    float e = expf(-u[r]);
    float sum = wave_sum64(e);
    y[r] = e / sum;
    Ya[(size_t)(row0 + r) * NCLS + lane] = y[r];
  }
  __syncthreads();  // nbl ready; own Y0 stores complete

  int mygen = 1;
  // grid barrier: publish Y0
  if (threadIdx.x == 0) {
    __threadfence();
    int old = atomicAdd(&gs->count, 1);
    if (old == PBLK - 1) { gs->count = 0; __threadfence(); atomicAdd(&gs->gen, 1); }
    while (__hip_atomic_load(&gs->gen, __ATOMIC_ACQUIRE, __HIP_MEMORY_SCOPE_AGENT) < mygen)
      __builtin_amdgcn_s_sleep(1);
    __threadfence();
  }
  __syncthreads();
  ++mygen;

  for (int iter = 0; iter < MAXSTEPS; ++iter) {
    const float* __restrict__ Yin = (iter & 1) ? Yb : Ya;
    float* __restrict__ Yout = (iter & 1) ? Ya : Yb;
    double ew = 0.0;
#pragma unroll
    for (int r = 0; r < 4; ++r) {
      const int lr = w * 4 + r;
      float pw = 0.f;
#pragma unroll
      for (int k = 0; k < KNN; ++k)
        pw += Yin[(size_t)nbl[lr][k] * NCLS + lane];
      float e = expf(pw - u[r]);
      float sum = wave_sum64(e);
      y[r] = e / sum;
      Yout[(size_t)(row0 + r) * NCLS + lane] = y[r];
      ew += -(double)logf(sum);
    }
    if (lane == 0) sE[w] = ew;
    __syncthreads();  // sE ready + all Y stores drained
    if (threadIdx.x == 0) {
      gs->Epart[b] = ((sE[0] + sE[1]) + (sE[2] + sE[3])) +
                     ((sE[4] + sE[5]) + (sE[6] + sE[7]));
      __threadfence();  // release Epart + this block's Y
      int old = atomicAdd(&gs->count, 1);
      isLast = (old == PBLK - 1) ? 1 : 0;
    }
    __syncthreads();
    if (isLast && threadIdx.x < 64) {  // one wave: parallel E reduction
      __threadfence();  // acquire all Epart
      double s = (gs->Epart[lane] + gs->Epart[lane + 64]) +
                 (gs->Epart[lane + 128] + gs->Epart[lane + 192]);
      s = wave_sum64d(s);
      if (lane == 0) {
        double E = s;
        int conv = (iter > 1) && (fabs(E - gs->Eold) <= 1e-8 * fabs(gs->Eold));
        gs->flag = conv;
        if (!conv) gs->Eold = E;
        gs->count = 0;
        __threadfence();
        atomicAdd(&gs->gen, 1);  // release epoch
      }
    }
    if (threadIdx.x == 0) {
      while (__hip_atomic_load(&gs->gen, __ATOMIC_ACQUIRE, __HIP_MEMORY_SCOPE_AGENT) < mygen)
        __builtin_amdgcn_s_sleep(1);
      __threadfence();  // acquire other blocks' Y + flag
      sflag = gs->flag;
    }
    __syncthreads();
    ++mygen;
    if (sflag) break;  // uniform across grid
  }

  // y regs hold the final iteration's values for this block's rows
#pragma unroll
  for (int r = 0; r < 4; ++r)
    out[(size_t)(row0 + r) * NCLS + lane] = y[r];
}

// ---------------- 0. state init ----------------
__global__ void k_init(GS* gs) {
  if (threadIdx.x == 0) {
    gs->Eold = (double)INFINITY;
    gs->count = 0; gs->gen = 0; gs->flag = 0;
  }
}

extern "C" void kernel_launch(void* const* d_in, const int* in_sizes, int n_in,
                              void* d_out, int out_size, void* d_ws, size_t ws_size,
                              hipStream_t stream) {
  (void)in_sizes; (void)n_in; (void)out_size; (void)ws_size;
  const float* scores = (const float*)d_in[0];
  const float* feats  = (const float*)d_in[1];
  float* out = (float*)d_out;
  char* ws = (char*)d_ws;
  // workspace layout (256B-aligned); total ~9.8 MB
  uint4*  fb    = (uint4*)(ws + 0);          //  4 MB pre-swizzled bf16 tiles
  float*  Ya    = (float*)(ws + 4194304);    //  2 MB
  float*  Yb    = (float*)(ws + 6291456);    //  2 MB
  double* sqd   = (double*)(ws + 8388608);   // 64 KB
  float*  nrm   = (float*)(ws + 8454144);    // 32 KB
  int*    candp = (int*)(ws + 8486912);      //  1 MB (4 splits x 8192 x 8)
  int*    nbr   = (int*)(ws + 9535488);      // 256 KB
  GS*     gs    = (GS*)(ws + 9791744);       // ~2.1 KB

  k_init<<<1, 64, 0, stream>>>(gs);
  k_normalize<<<NROWS / 4, 256, 0, stream>>>(feats, (uint2*)fb, nrm, sqd);
  k_gram<<<(NROWS / 64) * NSPLIT, 256, 0, stream>>>(fb, candp);
  k_refine<<<NROWS / 4, 256, 0, stream>>>(feats, nrm, sqd, candp, nbr);
  k_solve<<<PBLK, 512, 0, stream>>>(scores, nbr, Ya, Yb, out, gs);
}